// Round 3
// baseline (162.829 us; speedup 1.0000x reference)
//
#include <hip/hip_runtime.h>

#define ZD   128
#define NP   32
#define HID  256
#define INML 64
#define SPB  8
#define NBLK (4096 / SPB)

__device__ __forceinline__ float softplus_f(float x) {
    return fmaxf(x, 0.0f) + log1pf(expf(-fabsf(x)));
}
__device__ __forceinline__ float sigmoid_f(float x) {
    return 1.0f / (1.0f + expf(-x));
}

__global__ __launch_bounds__(256, 2) void chnn_main(
    const float* __restrict__ z, const float* __restrict__ mp,
    const float* __restrict__ W0, const float* __restrict__ b0,
    const float* __restrict__ W1, const float* __restrict__ b1,
    const float* __restrict__ W2, const float* __restrict__ b2,
    const float* __restrict__ W3,
    float* __restrict__ out)
{
    // activations laid out [unit][sample]: per-j reads are 16B-aligned float4 broadcasts
    __shared__ __align__(16) float rsh[INML][SPB];
    __shared__ __align__(16) float vsh[INML][SPB];
    __shared__ __align__(16) float gsh[INML][SPB];
    __shared__ __align__(16) float h0s[HID][SPB];   // fwd act L0; later g-partials
    __shared__ __align__(16) float h1s[HID][SPB];   // fwd act L1; later dB
    __shared__ float s0s[HID][SPB];
    __shared__ float s1s[HID][SPB];
    __shared__ __align__(16) float dAs[HID][SPB];   // dA; later d0
    __shared__ float invm[NP];
    __shared__ double invmd[NP];
    __shared__ float ge[SPB][NP][2], gd[SPB][NP][2];
    __shared__ double Sdd[SPB][NP], Sed[SPB][NP], Ked[SPB][NP];
    __shared__ double b0d[SPB][NP], b1d[SPB][NP];   // become X1, X0 in place
    __shared__ double wfac[SPB][NP], dinv[SPB][NP];

    const int tid = threadIdx.x;
    const long sbase = (long)blockIdx.x * SPB;

    if (tid < NP) {
        double e = exp(-(double)mp[tid]);
        invmd[tid] = e;
        invm[tid] = (float)e;
    }

    // ---- load z (8 samples x 128) ----
    const float* zb = z + sbase * ZD;
    #pragma unroll
    for (int k = 0; k < 4; ++k) {
        int e = k * 256 + tid;          // 0..1023
        int s = e >> 7, idx = e & 127;
        float val = zb[e];
        if (idx < 64) rsh[idx][s] = val;
        else          vsh[idx - 64][s] = val;    // raw p for now
    }
    __syncthreads();
    {   // p -> v = inv_m * p   (flat e = j*8+s, particle n = e>>4)
        float* pv = &vsh[0][0];
        #pragma unroll
        for (int k = 0; k < 2; ++k) {
            int e = k * 256 + tid;
            pv[e] *= invm[e >> 4];
        }
    }
    __syncthreads();

    float acc[SPB];

    // ---- layer 0: pre0 = r @ W0 + b0 (coalesced column reads) ----
    {
        float bb = b0[tid];
        #pragma unroll
        for (int s = 0; s < SPB; ++s) acc[s] = bb;
        #pragma unroll 4
        for (int j = 0; j < INML; ++j) {
            float w = W0[j * 256 + tid];
            float4 ra = *(const float4*)&rsh[j][0];
            float4 rb = *(const float4*)&rsh[j][4];
            acc[0] += ra.x * w; acc[1] += ra.y * w; acc[2] += ra.z * w; acc[3] += ra.w * w;
            acc[4] += rb.x * w; acc[5] += rb.y * w; acc[6] += rb.z * w; acc[7] += rb.w * w;
        }
        #pragma unroll
        for (int s = 0; s < SPB; ++s) {
            s0s[tid][s] = sigmoid_f(acc[s]);
            h0s[tid][s] = softplus_f(acc[s]);
        }
    }
    __syncthreads();

    // ---- layer 1 ----
    {
        float bb = b1[tid];
        #pragma unroll
        for (int s = 0; s < SPB; ++s) acc[s] = bb;
        #pragma unroll 4
        for (int j = 0; j < HID; ++j) {
            float w = W1[j * 256 + tid];
            float4 ra = *(const float4*)&h0s[j][0];
            float4 rb = *(const float4*)&h0s[j][4];
            acc[0] += ra.x * w; acc[1] += ra.y * w; acc[2] += ra.z * w; acc[3] += ra.w * w;
            acc[4] += rb.x * w; acc[5] += rb.y * w; acc[6] += rb.z * w; acc[7] += rb.w * w;
        }
        #pragma unroll
        for (int s = 0; s < SPB; ++s) {
            s1s[tid][s] = sigmoid_f(acc[s]);
            h1s[tid][s] = softplus_f(acc[s]);
        }
    }
    __syncthreads();

    // ---- layer 2 + start backward: dA[t] = W3[t] * sigmoid(pre2[t]) ----
    {
        float bb = b2[tid];
        #pragma unroll
        for (int s = 0; s < SPB; ++s) acc[s] = bb;
        #pragma unroll 4
        for (int j = 0; j < HID; ++j) {
            float w = W2[j * 256 + tid];
            float4 ra = *(const float4*)&h1s[j][0];
            float4 rb = *(const float4*)&h1s[j][4];
            acc[0] += ra.x * w; acc[1] += ra.y * w; acc[2] += ra.z * w; acc[3] += ra.w * w;
            acc[4] += rb.x * w; acc[5] += rb.y * w; acc[6] += rb.z * w; acc[7] += rb.w * w;
        }
        float w3 = W3[tid];
        #pragma unroll
        for (int s = 0; s < SPB; ++s) dAs[tid][s] = w3 * sigmoid_f(acc[s]);
    }
    __syncthreads();

    // ---- dB[t] = s1[t] * sum_j dA[j] * W2[t,j]   (per-lane row gather, 16B loads) ----
    {
        #pragma unroll
        for (int s = 0; s < SPB; ++s) acc[s] = 0.0f;
        const float4* wrow = (const float4*)(W2 + tid * 256);
        #pragma unroll 2
        for (int j4 = 0; j4 < 64; ++j4) {
            float4 wv = wrow[j4];
            float wk[4] = {wv.x, wv.y, wv.z, wv.w};
            #pragma unroll
            for (int k = 0; k < 4; ++k) {
                float w = wk[k];
                int j = j4 * 4 + k;
                float4 ra = *(const float4*)&dAs[j][0];
                float4 rb = *(const float4*)&dAs[j][4];
                acc[0] += ra.x * w; acc[1] += ra.y * w; acc[2] += ra.z * w; acc[3] += ra.w * w;
                acc[4] += rb.x * w; acc[5] += rb.y * w; acc[6] += rb.z * w; acc[7] += rb.w * w;
            }
        }
        #pragma unroll
        for (int s = 0; s < SPB; ++s) h1s[tid][s] = acc[s] * s1s[tid][s];
    }
    __syncthreads();

    // ---- d0[t] = s0[t] * sum_j dB[j] * W1[t,j] ----
    {
        #pragma unroll
        for (int s = 0; s < SPB; ++s) acc[s] = 0.0f;
        const float4* wrow = (const float4*)(W1 + tid * 256);
        #pragma unroll 2
        for (int j4 = 0; j4 < 64; ++j4) {
            float4 wv = wrow[j4];
            float wk[4] = {wv.x, wv.y, wv.z, wv.w};
            #pragma unroll
            for (int k = 0; k < 4; ++k) {
                float w = wk[k];
                int j = j4 * 4 + k;
                float4 ra = *(const float4*)&h1s[j][0];
                float4 rb = *(const float4*)&h1s[j][4];
                acc[0] += ra.x * w; acc[1] += ra.y * w; acc[2] += ra.z * w; acc[3] += ra.w * w;
                acc[4] += rb.x * w; acc[5] += rb.y * w; acc[6] += rb.z * w; acc[7] += rb.w * w;
            }
        }
        #pragma unroll
        for (int s = 0; s < SPB; ++s) dAs[tid][s] = acc[s] * s0s[tid][s];
    }
    __syncthreads();

    // ---- g[i] = sum_t d0[t] * W0[i,t] : 4 partial chunks of 64 ----
    {
        int q = tid >> 6, i = tid & 63;
        #pragma unroll
        for (int s = 0; s < SPB; ++s) acc[s] = 0.0f;
        const float4* wrow = (const float4*)(W0 + i * 256 + q * 64);
        #pragma unroll 2
        for (int j4 = 0; j4 < 16; ++j4) {
            float4 wv = wrow[j4];
            float wk[4] = {wv.x, wv.y, wv.z, wv.w};
            #pragma unroll
            for (int k = 0; k < 4; ++k) {
                float w = wk[k];
                int tt = q * 64 + j4 * 4 + k;
                float4 ra = *(const float4*)&dAs[tt][0];
                float4 rb = *(const float4*)&dAs[tt][4];
                acc[0] += ra.x * w; acc[1] += ra.y * w; acc[2] += ra.z * w; acc[3] += ra.w * w;
                acc[4] += rb.x * w; acc[5] += rb.y * w; acc[6] += rb.z * w; acc[7] += rb.w * w;
            }
        }
        #pragma unroll
        for (int s = 0; s < SPB; ++s) h0s[tid][s] = acc[s];
    }
    __syncthreads();
    if (tid < 64) {
        #pragma unroll
        for (int s = 0; s < SPB; ++s)
            gsh[tid][s] = h0s[tid][s] + h0s[64 + tid][s] + h0s[128 + tid][s] + h0s[192 + tid][s];
    }
    __syncthreads();

    // ---- constraint assembly (fp64): S tridiag SPD, K tridiag antisym, b0, b1 ----
    {
        int s = tid >> 5, c = tid & 31;
        double gx, gy, gdx, gdy;
        if (c == 0) {
            double r0x = rsh[0][s], r0y = rsh[1][s];
            double v0x = vsh[0][s], v0y = vsh[1][s];
            gx = 2.0 * r0x; gy = 2.0 * r0y; gdx = 2.0 * v0x; gdy = 2.0 * v0y;
            Sdd[s][0] = invmd[0] * (gx * gx + gy * gy);
            b0d[s][0] = gx * v0x + gy * v0y;
            b1d[s][0] = gdx * v0x + gdy * v0y
                      - invmd[0] * (gx * (double)gsh[0][s] + gy * (double)gsh[1][s]);
        } else {
            int a = 2 * (c - 1), b = 2 * c;
            double dvx = (double)vsh[a][s] - (double)vsh[b][s];
            double dvy = (double)vsh[a + 1][s] - (double)vsh[b + 1][s];
            gx = 2.0 * ((double)rsh[a][s] - (double)rsh[b][s]);
            gy = 2.0 * ((double)rsh[a + 1][s] - (double)rsh[b + 1][s]);
            gdx = 2.0 * dvx; gdy = 2.0 * dvy;
            Sdd[s][c] = (invmd[c - 1] + invmd[c]) * (gx * gx + gy * gy);
            b0d[s][c] = gx * dvx + gy * dvy;
            double mgx = invmd[c - 1] * (double)gsh[a][s]     - invmd[c] * (double)gsh[b][s];
            double mgy = invmd[c - 1] * (double)gsh[a + 1][s] - invmd[c] * (double)gsh[b + 1][s];
            b1d[s][c] = gdx * dvx + gdy * dvy - (gx * mgx + gy * mgy);
        }
        ge[s][c][0] = (float)gx;  ge[s][c][1] = (float)gy;
        gd[s][c][0] = (float)gdx; gd[s][c][1] = (float)gdy;
        __syncthreads();
        if (c < 31) {
            double g1x = ge[s][c + 1][0], g1y = ge[s][c + 1][1];
            double q1x = gd[s][c + 1][0], q1y = gd[s][c + 1][1];
            if (c == 0) {
                Sed[s][0] = invmd[0] * (gx * g1x + gy * g1y);
                Ked[s][0] = invmd[0] * ((gdx * g1x + gdy * g1y) - (gx * q1x + gy * q1y));
            } else {
                Sed[s][c] = -invmd[c] * (gx * g1x + gy * g1y);
                Ked[s][c] =  invmd[c] * ((gx * q1x + gy * q1y) - (gdx * g1x + gdy * g1y));
            }
        }
    }
    __syncthreads();

    // ---- fp64 Thomas: factor S, solve S X1 = b0 (in place in b0d) ----
    if (tid < SPB) {
        int s = tid;
        double d = Sdd[s][0];
        if (d == 0.0) d = 1e-300;
        dinv[s][0] = 1.0 / d;
        double y = b0d[s][0];
        for (int c = 1; c < NP; ++c) {
            double e = Sed[s][c - 1];
            double w = e * dinv[s][c - 1];
            wfac[s][c - 1] = w;
            d = Sdd[s][c] - w * e;
            if (d == 0.0) d = 1e-300;
            dinv[s][c] = 1.0 / d;
            y = b0d[s][c] - w * y;
            b0d[s][c] = y;
        }
        double x = b0d[s][31] * dinv[s][31];
        b0d[s][31] = x;
        for (int c = 30; c >= 0; --c) {
            x = (b0d[s][c] - Sed[s][c] * x) * dinv[s][c];
            b0d[s][c] = x;
        }
    }
    __syncthreads();

    // ---- rhs2 = K X1 - b1 (in place in b1d) ----
    {
        int s = tid >> 5, c = tid & 31;
        double kx = 0.0;
        if (c < 31) kx += Ked[s][c] * b0d[s][c + 1];
        if (c > 0)  kx -= Ked[s][c - 1] * b0d[s][c - 1];
        b1d[s][c] = kx - b1d[s][c];
    }
    __syncthreads();

    // ---- solve S X0 = rhs2 with stored factors (in place in b1d) ----
    if (tid < SPB) {
        int s = tid;
        double y = b1d[s][0];
        for (int c = 1; c < NP; ++c) {
            y = b1d[s][c] - wfac[s][c - 1] * y;
            b1d[s][c] = y;
        }
        double x = b1d[s][31] * dinv[s][31];
        b1d[s][31] = x;
        for (int c = 30; c >= 0; --c) {
            x = (b1d[s][c] - Sed[s][c] * x) * dinv[s][c];
            b1d[s][c] = x;
        }
    }
    __syncthreads();

    // ---- output: [v - M^-1 G X1 ; -g + G X0 + Gdot X1]   (X1=b0d, X0=b1d) ----
    float* ob = out + sbase * ZD;
    #pragma unroll
    for (int k = 0; k < 4; ++k) {
        int e = k * 256 + tid;
        int s = e >> 7, idx = e & 127;
        int j = idx & 63;
        int n = j >> 1, d = j & 1;
        float res;
        if (idx < 64) {
            double Gx1 = (n == 0) ? (double)ge[s][0][d] * b0d[s][0]
                                  : -(double)ge[s][n][d] * b0d[s][n];
            if (n < 31) Gx1 += (double)ge[s][n + 1][d] * b0d[s][n + 1];
            res = (float)((double)vsh[j][s] - invmd[n] * Gx1);
        } else {
            double Gx0 = (n == 0) ? (double)ge[s][0][d] * b1d[s][0]
                                  : -(double)ge[s][n][d] * b1d[s][n];
            if (n < 31) Gx0 += (double)ge[s][n + 1][d] * b1d[s][n + 1];
            double Gd1 = (n == 0) ? (double)gd[s][0][d] * b0d[s][0]
                                  : -(double)gd[s][n][d] * b0d[s][n];
            if (n < 31) Gd1 += (double)gd[s][n + 1][d] * b0d[s][n + 1];
            res = (float)(-(double)gsh[j][s] + Gx0 + Gd1);
        }
        ob[e] = res;
    }
}

extern "C" void kernel_launch(void* const* d_in, const int* in_sizes, int n_in,
                              void* d_out, int out_size, void* d_ws, size_t ws_size,
                              hipStream_t stream) {
    // inputs: 0=t, 1=z, 2=m_params, 3=W0, 4=b0, 5=W1, 6=b1, 7=W2, 8=b2, 9=W3, 10=b3
    const float* z  = (const float*)d_in[1];
    const float* mp = (const float*)d_in[2];
    const float* W0 = (const float*)d_in[3];
    const float* b0 = (const float*)d_in[4];
    const float* W1 = (const float*)d_in[5];
    const float* b1 = (const float*)d_in[6];
    const float* W2 = (const float*)d_in[7];
    const float* b2 = (const float*)d_in[8];
    const float* W3 = (const float*)d_in[9];

    chnn_main<<<NBLK, 256, 0, stream>>>(z, mp, W0, b0, W1, b1, W2, b2, W3,
                                        (float*)d_out);
}

// Round 4
// 157.731 us; speedup vs baseline: 1.0323x; 1.0323x over previous
//
#include <hip/hip_runtime.h>

#define ZD   128
#define NP   32
#define HID  256
#define INML 64
#define SPB  8
#define NBLK (4096 / SPB)

__device__ __forceinline__ float softplus_f(float x) {
    return fmaxf(x, 0.0f) + log1pf(expf(-fabsf(x)));
}
__device__ __forceinline__ float sigmoid_f(float x) {
    return 1.0f / (1.0f + expf(-x));
}

// fp32 weight transposes into workspace so backward GEMV loops stay coalesced.
// W0T[t*64+i]=W0[i*256+t]; W1T[j*256+t]=W1[t*256+j]; W2T likewise.
__global__ void prep_transpose(const float* __restrict__ W0,
                               const float* __restrict__ W1,
                               const float* __restrict__ W2,
                               float* __restrict__ W0T,
                               float* __restrict__ W1T,
                               float* __restrict__ W2T) {
    int idx = blockIdx.x * 256 + threadIdx.x;   // 147456 total
    if (idx < 64 * 256) {
        int t = idx >> 6, i = idx & 63;
        W0T[idx] = W0[i * 256 + t];
    } else if (idx < 64 * 256 + 256 * 256) {
        int k = idx - 64 * 256;
        int a = k >> 8, b = k & 255;
        W1T[k] = W1[b * 256 + a];
    } else {
        int k = idx - 64 * 256 - 256 * 256;
        int a = k >> 8, b = k & 255;
        W2T[k] = W2[b * 256 + a];
    }
}

__global__ __launch_bounds__(256, 2) void chnn_main(
    const float* __restrict__ z, const float* __restrict__ mp,
    const float* __restrict__ W0, const float* __restrict__ B0,
    const float* __restrict__ W1, const float* __restrict__ B1,
    const float* __restrict__ W2, const float* __restrict__ B2,
    const float* __restrict__ W3,
    const float* __restrict__ W0T, const float* __restrict__ W1T,
    const float* __restrict__ W2T,
    float* __restrict__ out)
{
    // wave w owns samples {2w,2w+1}; lane L owns units {4L..4L+3}.
    // Activation arrays [unit][sample]: per-j reads are b64 broadcasts of the
    // wave's own 2 samples; inner dim padded to 10 to spread write banks.
    __shared__ __align__(16) float rsh[INML][SPB];
    __shared__ __align__(16) float vsh[INML][SPB];
    __shared__ __align__(16) float gsh[INML][SPB];
    __shared__ __align__(16) float h0s[HID][10];
    __shared__ __align__(16) float h1s[HID][10];
    __shared__ __align__(16) float dAs[HID][10];
    __shared__ float invm[NP];
    __shared__ double invmd[NP];
    __shared__ float ge[SPB][NP][2], gd[SPB][NP][2];
    __shared__ double Sdd[SPB][NP], Sed[SPB][NP], Ked[SPB][NP];
    __shared__ double b0d[SPB][NP], b1d[SPB][NP];   // become X1, X0 in place
    __shared__ double wfac[SPB][NP], dinv[SPB][NP];

    const int tid = threadIdx.x;
    const int L   = tid & 63;        // lane
    const int wv_ = tid >> 6;        // wave 0..3
    const int u4  = 4 * L;           // first of my 4 units
    const int sc  = 2 * wv_;         // first of my 2 samples (block-local)
    const long sbase = (long)blockIdx.x * SPB;

    if (tid < NP) {
        double e = exp(-(double)mp[tid]);
        invmd[tid] = e;
        invm[tid] = (float)e;
    }

    // ---- load z (8 samples x 128), block-cooperative ----
    const float* zb = z + sbase * ZD;
    #pragma unroll
    for (int k = 0; k < 4; ++k) {
        int e = k * 256 + tid;          // 0..1023
        int s = e >> 7, idx = e & 127;
        float val = zb[e];
        if (idx < 64) rsh[idx][s] = val;
        else          vsh[idx - 64][s] = val;    // raw p for now
    }
    __syncthreads();
    {   // p -> v = inv_m * p   (flat e = j*8+s, particle n = e>>4)
        float* pv = &vsh[0][0];
        #pragma unroll
        for (int k = 0; k < 2; ++k) {
            int e = k * 256 + tid;
            pv[e] *= invm[e >> 4];
        }
    }
    __syncthreads();

    float a[4][2];      // accumulators: [unit q][sample s]
    float p0[4][2];     // pre-activation L0 (kept for sigmoid in backward)
    float p1[4][2];     // pre-activation L1

    // ---- L0: pre0 = r @ W0 + B0  (64-deep) ----
    {
        float4 bb = *(const float4*)&B0[u4];
        float bq[4] = {bb.x, bb.y, bb.z, bb.w};
        #pragma unroll
        for (int q = 0; q < 4; ++q) { a[q][0] = bq[q]; a[q][1] = bq[q]; }
        #pragma unroll 8
        for (int j = 0; j < INML; ++j) {
            float2 rv = *(const float2*)&rsh[j][sc];
            float4 wvv = *(const float4*)&W0[j * 256 + u4];
            float wq[4] = {wvv.x, wvv.y, wvv.z, wvv.w};
            #pragma unroll
            for (int q = 0; q < 4; ++q) {
                a[q][0] += wq[q] * rv.x;
                a[q][1] += wq[q] * rv.y;
            }
        }
        #pragma unroll
        for (int q = 0; q < 4; ++q) {
            p0[q][0] = a[q][0]; p0[q][1] = a[q][1];
            float2 hv; hv.x = softplus_f(a[q][0]); hv.y = softplus_f(a[q][1]);
            *(float2*)&h0s[u4 + q][sc] = hv;
        }
    }
    __syncthreads();

    // ---- L1 ----
    {
        float4 bb = *(const float4*)&B1[u4];
        float bq[4] = {bb.x, bb.y, bb.z, bb.w};
        #pragma unroll
        for (int q = 0; q < 4; ++q) { a[q][0] = bq[q]; a[q][1] = bq[q]; }
        #pragma unroll 8
        for (int j = 0; j < HID; ++j) {
            float2 hv = *(const float2*)&h0s[j][sc];
            float4 wvv = *(const float4*)&W1[j * 256 + u4];
            float wq[4] = {wvv.x, wvv.y, wvv.z, wvv.w};
            #pragma unroll
            for (int q = 0; q < 4; ++q) {
                a[q][0] += wq[q] * hv.x;
                a[q][1] += wq[q] * hv.y;
            }
        }
        #pragma unroll
        for (int q = 0; q < 4; ++q) {
            p1[q][0] = a[q][0]; p1[q][1] = a[q][1];
            float2 hv; hv.x = softplus_f(a[q][0]); hv.y = softplus_f(a[q][1]);
            *(float2*)&h1s[u4 + q][sc] = hv;
        }
    }
    __syncthreads();

    // ---- L2 + start backward: dA[t] = W3[t] * sigmoid(pre2[t]) ----
    {
        float4 bb = *(const float4*)&B2[u4];
        float bq[4] = {bb.x, bb.y, bb.z, bb.w};
        #pragma unroll
        for (int q = 0; q < 4; ++q) { a[q][0] = bq[q]; a[q][1] = bq[q]; }
        #pragma unroll 8
        for (int j = 0; j < HID; ++j) {
            float2 hv = *(const float2*)&h1s[j][sc];
            float4 wvv = *(const float4*)&W2[j * 256 + u4];
            float wq[4] = {wvv.x, wvv.y, wvv.z, wvv.w};
            #pragma unroll
            for (int q = 0; q < 4; ++q) {
                a[q][0] += wq[q] * hv.x;
                a[q][1] += wq[q] * hv.y;
            }
        }
        float4 w3v = *(const float4*)&W3[u4];
        float w3q[4] = {w3v.x, w3v.y, w3v.z, w3v.w};
        #pragma unroll
        for (int q = 0; q < 4; ++q) {
            float2 dv;
            dv.x = w3q[q] * sigmoid_f(a[q][0]);
            dv.y = w3q[q] * sigmoid_f(a[q][1]);
            *(float2*)&dAs[u4 + q][sc] = dv;
        }
    }
    __syncthreads();

    // ---- dB[t] = sigmoid(pre1[t]) * sum_j dA[j] * W2[t,j]  (W2T coalesced) ----
    {
        #pragma unroll
        for (int q = 0; q < 4; ++q) { a[q][0] = 0.0f; a[q][1] = 0.0f; }
        #pragma unroll 8
        for (int j = 0; j < HID; ++j) {
            float2 hv = *(const float2*)&dAs[j][sc];
            float4 wvv = *(const float4*)&W2T[j * 256 + u4];
            float wq[4] = {wvv.x, wvv.y, wvv.z, wvv.w};
            #pragma unroll
            for (int q = 0; q < 4; ++q) {
                a[q][0] += wq[q] * hv.x;
                a[q][1] += wq[q] * hv.y;
            }
        }
        #pragma unroll
        for (int q = 0; q < 4; ++q) {
            float2 dv;
            dv.x = a[q][0] * sigmoid_f(p1[q][0]);
            dv.y = a[q][1] * sigmoid_f(p1[q][1]);
            *(float2*)&h1s[u4 + q][sc] = dv;   // h1s reused as dB
        }
    }
    __syncthreads();

    // ---- d0[t] = sigmoid(pre0[t]) * sum_j dB[j] * W1[t,j]  (W1T coalesced) ----
    {
        #pragma unroll
        for (int q = 0; q < 4; ++q) { a[q][0] = 0.0f; a[q][1] = 0.0f; }
        #pragma unroll 8
        for (int j = 0; j < HID; ++j) {
            float2 hv = *(const float2*)&h1s[j][sc];
            float4 wvv = *(const float4*)&W1T[j * 256 + u4];
            float wq[4] = {wvv.x, wvv.y, wvv.z, wvv.w};
            #pragma unroll
            for (int q = 0; q < 4; ++q) {
                a[q][0] += wq[q] * hv.x;
                a[q][1] += wq[q] * hv.y;
            }
        }
        #pragma unroll
        for (int q = 0; q < 4; ++q) {
            float2 dv;
            dv.x = a[q][0] * sigmoid_f(p0[q][0]);
            dv.y = a[q][1] * sigmoid_f(p0[q][1]);
            *(float2*)&dAs[u4 + q][sc] = dv;   // dAs reused as d0
        }
    }
    __syncthreads();

    // ---- g[i] = sum_t d0[t] * W0[i,t]  (W0T coalesced; lane L -> i=L) ----
    {
        float ga0 = 0.0f, ga1 = 0.0f;
        #pragma unroll 8
        for (int t = 0; t < HID; ++t) {
            float w = W0T[t * 64 + L];
            float2 dv = *(const float2*)&dAs[t][sc];
            ga0 += w * dv.x;
            ga1 += w * dv.y;
        }
        float2 gv; gv.x = ga0; gv.y = ga1;
        *(float2*)&gsh[L][sc] = gv;
    }
    __syncthreads();

    // ---- constraint assembly (fp64): S tridiag SPD, K tridiag antisym, b0, b1 ----
    {
        int s = tid >> 5, c = tid & 31;
        double gx, gy, gdx, gdy;
        if (c == 0) {
            double r0x = rsh[0][s], r0y = rsh[1][s];
            double v0x = vsh[0][s], v0y = vsh[1][s];
            gx = 2.0 * r0x; gy = 2.0 * r0y; gdx = 2.0 * v0x; gdy = 2.0 * v0y;
            Sdd[s][0] = invmd[0] * (gx * gx + gy * gy);
            b0d[s][0] = gx * v0x + gy * v0y;
            b1d[s][0] = gdx * v0x + gdy * v0y
                      - invmd[0] * (gx * (double)gsh[0][s] + gy * (double)gsh[1][s]);
        } else {
            int aa = 2 * (c - 1), b = 2 * c;
            double dvx = (double)vsh[aa][s] - (double)vsh[b][s];
            double dvy = (double)vsh[aa + 1][s] - (double)vsh[b + 1][s];
            gx = 2.0 * ((double)rsh[aa][s] - (double)rsh[b][s]);
            gy = 2.0 * ((double)rsh[aa + 1][s] - (double)rsh[b + 1][s]);
            gdx = 2.0 * dvx; gdy = 2.0 * dvy;
            Sdd[s][c] = (invmd[c - 1] + invmd[c]) * (gx * gx + gy * gy);
            b0d[s][c] = gx * dvx + gy * dvy;
            double mgx = invmd[c - 1] * (double)gsh[aa][s]     - invmd[c] * (double)gsh[b][s];
            double mgy = invmd[c - 1] * (double)gsh[aa + 1][s] - invmd[c] * (double)gsh[b + 1][s];
            b1d[s][c] = gdx * dvx + gdy * dvy - (gx * mgx + gy * mgy);
        }
        ge[s][c][0] = (float)gx;  ge[s][c][1] = (float)gy;
        gd[s][c][0] = (float)gdx; gd[s][c][1] = (float)gdy;
        __syncthreads();
        if (c < 31) {
            double g1x = ge[s][c + 1][0], g1y = ge[s][c + 1][1];
            double q1x = gd[s][c + 1][0], q1y = gd[s][c + 1][1];
            if (c == 0) {
                Sed[s][0] = invmd[0] * (gx * g1x + gy * g1y);
                Ked[s][0] = invmd[0] * ((gdx * g1x + gdy * g1y) - (gx * q1x + gy * q1y));
            } else {
                Sed[s][c] = -invmd[c] * (gx * g1x + gy * g1y);
                Ked[s][c] =  invmd[c] * ((gx * q1x + gy * q1y) - (gdx * g1x + gdy * g1y));
            }
        }
    }
    __syncthreads();

    // ---- fp64 Thomas: factor S, solve S X1 = b0 (in place in b0d) ----
    if (tid < SPB) {
        int s = tid;
        double d = Sdd[s][0];
        if (d == 0.0) d = 1e-300;
        dinv[s][0] = 1.0 / d;
        double y = b0d[s][0];
        for (int c = 1; c < NP; ++c) {
            double e = Sed[s][c - 1];
            double w = e * dinv[s][c - 1];
            wfac[s][c - 1] = w;
            d = Sdd[s][c] - w * e;
            if (d == 0.0) d = 1e-300;
            dinv[s][c] = 1.0 / d;
            y = b0d[s][c] - w * y;
            b0d[s][c] = y;
        }
        double x = b0d[s][31] * dinv[s][31];
        b0d[s][31] = x;
        for (int c = 30; c >= 0; --c) {
            x = (b0d[s][c] - Sed[s][c] * x) * dinv[s][c];
            b0d[s][c] = x;
        }
    }
    __syncthreads();

    // ---- rhs2 = K X1 - b1 (in place in b1d) ----
    {
        int s = tid >> 5, c = tid & 31;
        double kx = 0.0;
        if (c < 31) kx += Ked[s][c] * b0d[s][c + 1];
        if (c > 0)  kx -= Ked[s][c - 1] * b0d[s][c - 1];
        b1d[s][c] = kx - b1d[s][c];
    }
    __syncthreads();

    // ---- solve S X0 = rhs2 with stored factors (in place in b1d) ----
    if (tid < SPB) {
        int s = tid;
        double y = b1d[s][0];
        for (int c = 1; c < NP; ++c) {
            y = b1d[s][c] - wfac[s][c - 1] * y;
            b1d[s][c] = y;
        }
        double x = b1d[s][31] * dinv[s][31];
        b1d[s][31] = x;
        for (int c = 30; c >= 0; --c) {
            x = (b1d[s][c] - Sed[s][c] * x) * dinv[s][c];
            b1d[s][c] = x;
        }
    }
    __syncthreads();

    // ---- output: [v - M^-1 G X1 ; -g + G X0 + Gdot X1]   (X1=b0d, X0=b1d) ----
    float* ob = out + sbase * ZD;
    #pragma unroll
    for (int k = 0; k < 4; ++k) {
        int e = k * 256 + tid;
        int s = e >> 7, idx = e & 127;
        int j = idx & 63;
        int n = j >> 1, d = j & 1;
        float res;
        if (idx < 64) {
            double Gx1 = (n == 0) ? (double)ge[s][0][d] * b0d[s][0]
                                  : -(double)ge[s][n][d] * b0d[s][n];
            if (n < 31) Gx1 += (double)ge[s][n + 1][d] * b0d[s][n + 1];
            res = (float)((double)vsh[j][s] - invmd[n] * Gx1);
        } else {
            double Gx0 = (n == 0) ? (double)ge[s][0][d] * b1d[s][0]
                                  : -(double)ge[s][n][d] * b1d[s][n];
            if (n < 31) Gx0 += (double)ge[s][n + 1][d] * b1d[s][n + 1];
            double Gd1 = (n == 0) ? (double)gd[s][0][d] * b0d[s][0]
                                  : -(double)gd[s][n][d] * b0d[s][n];
            if (n < 31) Gd1 += (double)gd[s][n + 1][d] * b0d[s][n + 1];
            res = (float)(-(double)gsh[j][s] + Gx0 + Gd1);
        }
        ob[e] = res;
    }
}

extern "C" void kernel_launch(void* const* d_in, const int* in_sizes, int n_in,
                              void* d_out, int out_size, void* d_ws, size_t ws_size,
                              hipStream_t stream) {
    // inputs: 0=t, 1=z, 2=m_params, 3=W0, 4=b0, 5=W1, 6=b1, 7=W2, 8=b2, 9=W3, 10=b3
    const float* z  = (const float*)d_in[1];
    const float* mp = (const float*)d_in[2];
    const float* W0 = (const float*)d_in[3];
    const float* B0 = (const float*)d_in[4];
    const float* W1 = (const float*)d_in[5];
    const float* B1 = (const float*)d_in[6];
    const float* W2 = (const float*)d_in[7];
    const float* B2 = (const float*)d_in[8];
    const float* W3 = (const float*)d_in[9];

    float* W0T = (float*)d_ws;               // 16384 floats
    float* W1T = W0T + 64 * 256;             // 65536 floats
    float* W2T = W1T + 256 * 256;            // 65536 floats

    prep_transpose<<<576, 256, 0, stream>>>(W0, W1, W2, W0T, W1T, W2T);
    chnn_main<<<NBLK, 256, 0, stream>>>(z, mp, W0, B0, W1, B1, W2, B2, W3,
                                        W0T, W1T, W2T, (float*)d_out);
}

// Round 5
// 142.179 us; speedup vs baseline: 1.1452x; 1.1094x over previous
//
#include <hip/hip_runtime.h>

#define ZD   128
#define NP   32
#define HID  256
#define INML 64
#define SPB  8
#define NBLK (4096 / SPB)
#define RST  36   // redbuf per-lane stride (floats): 16B-aligned, modest conflicts

__device__ __forceinline__ float softplus_f(float x) {
    return fmaxf(x, 0.0f) + log1pf(expf(-fabsf(x)));
}
__device__ __forceinline__ float sigmoid_f(float x) {
    return 1.0f / (1.0f + expf(-x));
}
__device__ __forceinline__ float rdlane(float v, int j) {
    return __int_as_float(__builtin_amdgcn_readlane(__float_as_int(v), j));
}

// fp32 weight transposes so backward K-loops read coalesced columns.
// W0T[t*64+i]=W0[i*256+t]; W1T[j*256+t]=W1[t*256+j]; W2T likewise.
__global__ void prep_transpose(const float* __restrict__ W0,
                               const float* __restrict__ W1,
                               const float* __restrict__ W2,
                               float* __restrict__ W0T,
                               float* __restrict__ W1T,
                               float* __restrict__ W2T) {
    int idx = blockIdx.x * 256 + threadIdx.x;   // 147456 total
    if (idx < 64 * 256) {
        int t = idx >> 6, i = idx & 63;
        W0T[idx] = W0[i * 256 + t];
    } else if (idx < 64 * 256 + 256 * 256) {
        int k = idx - 64 * 256;
        int a = k >> 8, b = k & 255;
        W1T[k] = W1[b * 256 + a];
    } else {
        int k = idx - 64 * 256 - 256 * 256;
        int a = k >> 8, b = k & 255;
        W2T[k] = W2[b * 256 + a];
    }
}

__global__ __launch_bounds__(256, 2) void chnn_main(
    const float* __restrict__ z, const float* __restrict__ mp,
    const float* __restrict__ W0, const float* __restrict__ B0,
    const float* __restrict__ W1, const float* __restrict__ B1,
    const float* __restrict__ W2, const float* __restrict__ B2,
    const float* __restrict__ W3,
    const float* __restrict__ W0T, const float* __restrict__ W1T,
    const float* __restrict__ W2T,
    float* __restrict__ out)
{
    // Register-resident GEMV chain: thread t owns unit t (8 samples).
    // K-256 passes: wave w covers k in [64w,64w+64) for ALL 256 units
    // (4 units/lane), activations via v_readlane from own lanes,
    // weights read ONCE per block per pass (coalesced float4).
    __shared__ __align__(16) float rsh[INML][SPB];
    __shared__ __align__(16) float vsh[INML][SPB];
    __shared__ __align__(16) float gsh[INML][SPB];
    __shared__ __align__(16) float redbuf[4][64][RST];   // cross-wave partials
    __shared__ float invm[NP];
    __shared__ double invmd[NP];
    __shared__ float ge[SPB][NP][2], gd[SPB][NP][2];
    __shared__ double Sdd[SPB][NP], Sed[SPB][NP], Ked[SPB][NP];
    __shared__ double b0d[SPB][NP], b1d[SPB][NP];   // become X1, X0 in place
    __shared__ double wfac[SPB][NP], dinv[SPB][NP];

    const int tid = threadIdx.x;
    const int L   = tid & 63;        // lane
    const int wv  = tid >> 6;        // wave 0..3
    const long sbase = (long)blockIdx.x * SPB;

    if (tid < NP) {
        double e = exp(-(double)mp[tid]);
        invmd[tid] = e;
        invm[tid] = (float)e;
    }

    // ---- load z (8 samples x 128), block-cooperative ----
    const float* zb = z + sbase * ZD;
    #pragma unroll
    for (int k = 0; k < 4; ++k) {
        int e = k * 256 + tid;          // 0..1023
        int s = e >> 7, idx = e & 127;
        float val = zb[e];
        if (idx < 64) rsh[idx][s] = val;
        else          vsh[idx - 64][s] = val;    // raw p for now
    }
    __syncthreads();
    {   // p -> v = inv_m * p   (flat e = j*8+s, particle n = e>>4)
        float* pv = &vsh[0][0];
        #pragma unroll
        for (int k = 0; k < 2; ++k) {
            int e = k * 256 + tid;
            pv[e] *= invm[e >> 4];
        }
    }
    __syncthreads();

    // thread-local register state
    float r_reg[8];                  // r[L][s] (same in every wave)
    {
        float4 ra = *(const float4*)&rsh[L][0];
        float4 rb = *(const float4*)&rsh[L][4];
        r_reg[0]=ra.x; r_reg[1]=ra.y; r_reg[2]=ra.z; r_reg[3]=ra.w;
        r_reg[4]=rb.x; r_reg[5]=rb.y; r_reg[6]=rb.z; r_reg[7]=rb.w;
    }

    float hA[8], hB[8], p0[8], p1[8], pre[8];

    // K=256 GEMV pass: pre[s] = bias + sum_k hreg-broadcast * Wp[k*256+unit]
    auto pass256 = [&](const float* __restrict__ Wp, const float* hreg,
                       float* out8, float bias) {
        float a4[4][8];
        #pragma unroll
        for (int q = 0; q < 4; ++q)
            #pragma unroll
            for (int s = 0; s < 8; ++s) a4[q][s] = 0.0f;
        const float* wb = Wp + (wv << 6) * 256 + 4 * L;
        #pragma unroll 8
        for (int j = 0; j < 64; ++j) {
            float4 wvv = *(const float4*)(wb + j * 256);
            #pragma unroll
            for (int s = 0; s < 8; ++s) {
                float hs = rdlane(hreg[s], j);
                a4[0][s] = fmaf(wvv.x, hs, a4[0][s]);
                a4[1][s] = fmaf(wvv.y, hs, a4[1][s]);
                a4[2][s] = fmaf(wvv.z, hs, a4[2][s]);
                a4[3][s] = fmaf(wvv.w, hs, a4[3][s]);
            }
        }
        float* myr = &redbuf[wv][L][0];
        #pragma unroll
        for (int q = 0; q < 4; ++q) {
            float4 v0; v0.x=a4[q][0]; v0.y=a4[q][1]; v0.z=a4[q][2]; v0.w=a4[q][3];
            float4 v1; v1.x=a4[q][4]; v1.y=a4[q][5]; v1.z=a4[q][6]; v1.w=a4[q][7];
            *(float4*)(myr + q * 8)     = v0;
            *(float4*)(myr + q * 8 + 4) = v1;
        }
        __syncthreads();
        #pragma unroll
        for (int s = 0; s < 8; ++s) out8[s] = bias;
        #pragma unroll
        for (int w2 = 0; w2 < 4; ++w2) {
            const float* src = &redbuf[w2][tid >> 2][(tid & 3) * 8];
            float4 x0 = *(const float4*)src;
            float4 x1 = *(const float4*)(src + 4);
            out8[0]+=x0.x; out8[1]+=x0.y; out8[2]+=x0.z; out8[3]+=x0.w;
            out8[4]+=x1.x; out8[5]+=x1.y; out8[6]+=x1.z; out8[7]+=x1.w;
        }
        __syncthreads();   // redbuf safe for reuse
    };

    // ---- L0: pre0[tid][s] = B0[tid] + sum_{j<64} r[j][s]*W0[j*256+tid] ----
    {
        float bb = B0[tid];
        #pragma unroll
        for (int s = 0; s < 8; ++s) pre[s] = bb;
        #pragma unroll 8
        for (int j = 0; j < 64; ++j) {
            float w_ = W0[j * 256 + tid];
            #pragma unroll
            for (int s = 0; s < 8; ++s) {
                float rs = rdlane(r_reg[s], j);
                pre[s] = fmaf(w_, rs, pre[s]);
            }
        }
        #pragma unroll
        for (int s = 0; s < 8; ++s) { p0[s] = pre[s]; hA[s] = softplus_f(pre[s]); }
    }

    // ---- L1: h1 = softplus(hA @ W1 + B1) ----
    pass256(W1, hA, pre, B1[tid]);
    #pragma unroll
    for (int s = 0; s < 8; ++s) { p1[s] = pre[s]; hB[s] = softplus_f(pre[s]); }

    // ---- L2 + head: dA[tid][s] = W3[tid] * sigmoid(pre2) ----
    pass256(W2, hB, pre, B2[tid]);
    {
        float w3 = W3[tid];
        #pragma unroll
        for (int s = 0; s < 8; ++s) hA[s] = w3 * sigmoid_f(pre[s]);   // hA = dA
    }

    // ---- dB[tid][s] = sigmoid(p1) * sum_j dA[j]*W2[tid,j] ----
    pass256(W2T, hA, pre, 0.0f);
    #pragma unroll
    for (int s = 0; s < 8; ++s) hB[s] = pre[s] * sigmoid_f(p1[s]);    // hB = dB

    // ---- d0[tid][s] = sigmoid(p0) * sum_j dB[j]*W1[tid,j] ----
    pass256(W1T, hB, pre, 0.0f);
    #pragma unroll
    for (int s = 0; s < 8; ++s) hA[s] = pre[s] * sigmoid_f(p0[s]);    // hA = d0

    // ---- g[i] = sum_t d0[t]*W0[i,t]: lane L -> i=L, wave k-slice, reduce ----
    {
        float ga[8];
        #pragma unroll
        for (int s = 0; s < 8; ++s) ga[s] = 0.0f;
        const float* wb = W0T + (wv << 6) * 64 + L;
        #pragma unroll 8
        for (int j = 0; j < 64; ++j) {
            float w_ = wb[j * 64];
            #pragma unroll
            for (int s = 0; s < 8; ++s) {
                float ds = rdlane(hA[s], j);
                ga[s] = fmaf(w_, ds, ga[s]);
            }
        }
        float* myr = &redbuf[wv][L][0];
        float4 v0; v0.x=ga[0]; v0.y=ga[1]; v0.z=ga[2]; v0.w=ga[3];
        float4 v1; v1.x=ga[4]; v1.y=ga[5]; v1.z=ga[6]; v1.w=ga[7];
        *(float4*)(myr)     = v0;
        *(float4*)(myr + 4) = v1;
        __syncthreads();
        if (tid < 64) {
            float4 s0 = *(const float4*)&redbuf[0][tid][0];
            float4 s1 = *(const float4*)&redbuf[0][tid][4];
            #pragma unroll
            for (int w2 = 1; w2 < 4; ++w2) {
                float4 t0 = *(const float4*)&redbuf[w2][tid][0];
                float4 t1 = *(const float4*)&redbuf[w2][tid][4];
                s0.x+=t0.x; s0.y+=t0.y; s0.z+=t0.z; s0.w+=t0.w;
                s1.x+=t1.x; s1.y+=t1.y; s1.z+=t1.z; s1.w+=t1.w;
            }
            *(float4*)&gsh[tid][0] = s0;
            *(float4*)&gsh[tid][4] = s1;
        }
    }
    __syncthreads();

    // ---- constraint assembly (fp64): S tridiag SPD, K tridiag antisym, b0, b1 ----
    {
        int s = tid >> 5, c = tid & 31;
        double gx, gy, gdx, gdy;
        if (c == 0) {
            double r0x = rsh[0][s], r0y = rsh[1][s];
            double v0x = vsh[0][s], v0y = vsh[1][s];
            gx = 2.0 * r0x; gy = 2.0 * r0y; gdx = 2.0 * v0x; gdy = 2.0 * v0y;
            Sdd[s][0] = invmd[0] * (gx * gx + gy * gy);
            b0d[s][0] = gx * v0x + gy * v0y;
            b1d[s][0] = gdx * v0x + gdy * v0y
                      - invmd[0] * (gx * (double)gsh[0][s] + gy * (double)gsh[1][s]);
        } else {
            int aa = 2 * (c - 1), b = 2 * c;
            double dvx = (double)vsh[aa][s] - (double)vsh[b][s];
            double dvy = (double)vsh[aa + 1][s] - (double)vsh[b + 1][s];
            gx = 2.0 * ((double)rsh[aa][s] - (double)rsh[b][s]);
            gy = 2.0 * ((double)rsh[aa + 1][s] - (double)rsh[b + 1][s]);
            gdx = 2.0 * dvx; gdy = 2.0 * dvy;
            Sdd[s][c] = (invmd[c - 1] + invmd[c]) * (gx * gx + gy * gy);
            b0d[s][c] = gx * dvx + gy * dvy;
            double mgx = invmd[c - 1] * (double)gsh[aa][s]     - invmd[c] * (double)gsh[b][s];
            double mgy = invmd[c - 1] * (double)gsh[aa + 1][s] - invmd[c] * (double)gsh[b + 1][s];
            b1d[s][c] = gdx * dvx + gdy * dvy - (gx * mgx + gy * mgy);
        }
        ge[s][c][0] = (float)gx;  ge[s][c][1] = (float)gy;
        gd[s][c][0] = (float)gdx; gd[s][c][1] = (float)gdy;
        __syncthreads();
        if (c < 31) {
            double g1x = ge[s][c + 1][0], g1y = ge[s][c + 1][1];
            double q1x = gd[s][c + 1][0], q1y = gd[s][c + 1][1];
            if (c == 0) {
                Sed[s][0] = invmd[0] * (gx * g1x + gy * g1y);
                Ked[s][0] = invmd[0] * ((gdx * g1x + gdy * g1y) - (gx * q1x + gy * q1y));
            } else {
                Sed[s][c] = -invmd[c] * (gx * g1x + gy * g1y);
                Ked[s][c] =  invmd[c] * ((gx * q1x + gy * q1y) - (gdx * g1x + gdy * g1y));
            }
        }
    }
    __syncthreads();

    // ---- fp64 Thomas: factor S, solve S X1 = b0 (in place in b0d) ----
    if (tid < SPB) {
        int s = tid;
        double d = Sdd[s][0];
        if (d == 0.0) d = 1e-300;
        dinv[s][0] = 1.0 / d;
        double y = b0d[s][0];
        for (int c = 1; c < NP; ++c) {
            double e = Sed[s][c - 1];
            double w = e * dinv[s][c - 1];
            wfac[s][c - 1] = w;
            d = Sdd[s][c] - w * e;
            if (d == 0.0) d = 1e-300;
            dinv[s][c] = 1.0 / d;
            y = b0d[s][c] - w * y;
            b0d[s][c] = y;
        }
        double x = b0d[s][31] * dinv[s][31];
        b0d[s][31] = x;
        for (int c = 30; c >= 0; --c) {
            x = (b0d[s][c] - Sed[s][c] * x) * dinv[s][c];
            b0d[s][c] = x;
        }
    }
    __syncthreads();

    // ---- rhs2 = K X1 - b1 (in place in b1d) ----
    {
        int s = tid >> 5, c = tid & 31;
        double kx = 0.0;
        if (c < 31) kx += Ked[s][c] * b0d[s][c + 1];
        if (c > 0)  kx -= Ked[s][c - 1] * b0d[s][c - 1];
        b1d[s][c] = kx - b1d[s][c];
    }
    __syncthreads();

    // ---- solve S X0 = rhs2 with stored factors (in place in b1d) ----
    if (tid < SPB) {
        int s = tid;
        double y = b1d[s][0];
        for (int c = 1; c < NP; ++c) {
            y = b1d[s][c] - wfac[s][c - 1] * y;
            b1d[s][c] = y;
        }
        double x = b1d[s][31] * dinv[s][31];
        b1d[s][31] = x;
        for (int c = 30; c >= 0; --c) {
            x = (b1d[s][c] - Sed[s][c] * x) * dinv[s][c];
            b1d[s][c] = x;
        }
    }
    __syncthreads();

    // ---- output: [v - M^-1 G X1 ; -g + G X0 + Gdot X1]   (X1=b0d, X0=b1d) ----
    float* ob = out + sbase * ZD;
    #pragma unroll
    for (int k = 0; k < 4; ++k) {
        int e = k * 256 + tid;
        int s = e >> 7, idx = e & 127;
        int j = idx & 63;
        int n = j >> 1, d = j & 1;
        float res;
        if (idx < 64) {
            double Gx1 = (n == 0) ? (double)ge[s][0][d] * b0d[s][0]
                                  : -(double)ge[s][n][d] * b0d[s][n];
            if (n < 31) Gx1 += (double)ge[s][n + 1][d] * b0d[s][n + 1];
            res = (float)((double)vsh[j][s] - invmd[n] * Gx1);
        } else {
            double Gx0 = (n == 0) ? (double)ge[s][0][d] * b1d[s][0]
                                  : -(double)ge[s][n][d] * b1d[s][n];
            if (n < 31) Gx0 += (double)ge[s][n + 1][d] * b1d[s][n + 1];
            double Gd1 = (n == 0) ? (double)gd[s][0][d] * b0d[s][0]
                                  : -(double)gd[s][n][d] * b0d[s][n];
            if (n < 31) Gd1 += (double)gd[s][n + 1][d] * b0d[s][n + 1];
            res = (float)(-(double)gsh[j][s] + Gx0 + Gd1);
        }
        ob[e] = res;
    }
}

extern "C" void kernel_launch(void* const* d_in, const int* in_sizes, int n_in,
                              void* d_out, int out_size, void* d_ws, size_t ws_size,
                              hipStream_t stream) {
    // inputs: 0=t, 1=z, 2=m_params, 3=W0, 4=b0, 5=W1, 6=b1, 7=W2, 8=b2, 9=W3, 10=b3
    const float* z  = (const float*)d_in[1];
    const float* mp = (const float*)d_in[2];
    const float* W0 = (const float*)d_in[3];
    const float* B0 = (const float*)d_in[4];
    const float* W1 = (const float*)d_in[5];
    const float* B1 = (const float*)d_in[6];
    const float* W2 = (const float*)d_in[7];
    const float* B2 = (const float*)d_in[8];
    const float* W3 = (const float*)d_in[9];

    float* W0T = (float*)d_ws;               // 16384 floats
    float* W1T = W0T + 64 * 256;             // 65536 floats
    float* W2T = W1T + 256 * 256;            // 65536 floats

    prep_transpose<<<576, 256, 0, stream>>>(W0, W1, W2, W0T, W1T, W2T);
    chnn_main<<<NBLK, 256, 0, stream>>>(z, mp, W0, B0, W1, B1, W2, B2, W3,
                                        W0T, W1T, W2T, (float*)d_out);
}

// Round 6
// 136.595 us; speedup vs baseline: 1.1921x; 1.0409x over previous
//
#include <hip/hip_runtime.h>

#define ZD   128
#define NP   32
#define SPB  8
#define NBLK (4096 / SPB)

typedef __attribute__((ext_vector_type(8))) short bf16x8;   // 8 bf16 = 4 VGPRs
typedef __attribute__((ext_vector_type(4))) float f32x4;

// packed-weight element offsets (bf16 elements); lo copies at +TOTE
#define OFF_W0   0
#define OFF_W1   16384
#define OFF_W2   81920
#define OFF_W2T  147456
#define OFF_W1T  212992
#define OFF_W0T  278528
#define TOTE     294912

__device__ __forceinline__ float softplus_f(float x) {
    return fmaxf(x, 0.0f) + log1pf(expf(-fabsf(x)));
}
__device__ __forceinline__ float sigmoid_f(float x) {
    return 1.0f / (1.0f + expf(-x));
}
__device__ __forceinline__ unsigned short f2b(float f) {   // RNE float->bf16
    unsigned int u = __float_as_uint(f);
    unsigned int r = (u + 0x7FFFu + ((u >> 16) & 1u)) >> 16;
    return (unsigned short)r;
}
__device__ __forceinline__ float b2f(unsigned short h) {
    return __uint_as_float(((unsigned int)h) << 16);
}

// ---- pack weights (and transposes) into MFMA B-fragment order, split hi/lo ----
// fragment (kb,nt): lane L holds 8 consecutive k at n = nt*16+(L&15),
// k = kb*32+(L>>4)*8+j ; packed elem index = frag*512 + L*8 + j.
__global__ void prep_pack(const float* __restrict__ W0,
                          const float* __restrict__ W1,
                          const float* __restrict__ W2,
                          short* __restrict__ P) {
    int T = blockIdx.x * 256 + threadIdx.x;       // one thread = one lane-unit (8 elems)
    if (T >= 36864) return;
    const float* src; int base, NT, trans, lu, t = T;
    if (t < 2048)               { src = W0; base = OFF_W0;  NT = 16; trans = 0; lu = t; }
    else if ((t -= 2048) < 8192){ src = W1; base = OFF_W1;  NT = 16; trans = 0; lu = t; }
    else if ((t -= 8192) < 8192){ src = W2; base = OFF_W2;  NT = 16; trans = 0; lu = t; }
    else if ((t -= 8192) < 8192){ src = W2; base = OFF_W2T; NT = 16; trans = 1; lu = t; }
    else if ((t -= 8192) < 8192){ src = W1; base = OFF_W1T; NT = 16; trans = 1; lu = t; }
    else              { t -= 8192; src = W0; base = OFF_W0T; NT = 4; trans = 1; lu = t; }
    int frag = lu >> 6, lane = lu & 63;
    int kb = frag / NT, nt = frag - kb * NT;
    int n  = nt * 16 + (lane & 15);
    int k0 = kb * 32 + ((lane >> 4) << 3);
    int N  = NT * 16;
    bf16x8 hv, lv;
    #pragma unroll
    for (int j = 0; j < 8; ++j) {
        int k = k0 + j;
        float w = trans ? src[n * 256 + k] : src[k * N + n];
        unsigned short h = f2b(w);
        unsigned short l = f2b(w - b2f(h));
        hv[j] = (short)h;
        lv[j] = (short)l;
    }
    ((bf16x8*)(P + base))[lu]        = hv;
    ((bf16x8*)(P + TOTE + base))[lu] = lv;
}

// split-bf16 GEMM pass: acc[t] += A(act) x B(packed), 3 MFMAs per fragment.
template<int KB, int NT, int TPW>
__device__ __forceinline__ void gemm_mf(const short* __restrict__ BH,
                                        const short* __restrict__ BL,
                                        const unsigned short (*aH)[264],
                                        const unsigned short (*aL)[264],
                                        int L, int quad, int wv, f32x4* acc)
{
    #pragma unroll
    for (int kb = 0; kb < KB; ++kb) {
        bf16x8 ah = *(const bf16x8*)&aH[L & 15][kb * 32 + quad * 8];
        bf16x8 al = *(const bf16x8*)&aL[L & 15][kb * 32 + quad * 8];
        #pragma unroll
        for (int t = 0; t < TPW; ++t) {
            int frag = kb * NT + wv * TPW + t;
            bf16x8 bh = ((const bf16x8*)BH)[frag * 64 + L];
            bf16x8 bl = ((const bf16x8*)BL)[frag * 64 + L];
            acc[t] = __builtin_amdgcn_mfma_f32_16x16x32_bf16(ah, bh, acc[t], 0, 0, 0);
            acc[t] = __builtin_amdgcn_mfma_f32_16x16x32_bf16(ah, bl, acc[t], 0, 0, 0);
            acc[t] = __builtin_amdgcn_mfma_f32_16x16x32_bf16(al, bh, acc[t], 0, 0, 0);
        }
    }
}

__global__ __launch_bounds__(256, 2) void chnn_main(
    const float* __restrict__ z, const float* __restrict__ mp,
    const float* __restrict__ B0, const float* __restrict__ B1,
    const float* __restrict__ B2, const float* __restrict__ W3,
    const short* __restrict__ P,
    float* __restrict__ out)
{
    // act buffers [m=sample 0..7 (8..15 garbage, confined)][k], pitch 264 bf16
    __shared__ __align__(16) unsigned short actH[16][264];
    __shared__ __align__(16) unsigned short actL[16][264];
    __shared__ __align__(16) float rsh[64][SPB];
    __shared__ __align__(16) float vsh[64][SPB];
    __shared__ __align__(16) float gsh[64][SPB];
    __shared__ float invm[NP];
    __shared__ double invmd[NP];
    __shared__ float ge[SPB][NP][2], gd[SPB][NP][2];
    __shared__ double Sdd[SPB][NP], Sed[SPB][NP], Ked[SPB][NP];
    __shared__ double b0d[SPB][NP], b1d[SPB][NP];
    __shared__ double wfac[SPB][NP], dinv[SPB][NP];

    const int tid  = threadIdx.x;
    const int L    = tid & 63;
    const int wv   = tid >> 6;
    const int quad = L >> 4;
    const long sbase = (long)blockIdx.x * SPB;

    const short* W0h  = P + OFF_W0;   const short* W0l  = P + TOTE + OFF_W0;
    const short* W1h  = P + OFF_W1;   const short* W1l  = P + TOTE + OFF_W1;
    const short* W2h  = P + OFF_W2;   const short* W2l  = P + TOTE + OFF_W2;
    const short* W2Th = P + OFF_W2T;  const short* W2Tl = P + TOTE + OFF_W2T;
    const short* W1Th = P + OFF_W1T;  const short* W1Tl = P + TOTE + OFF_W1T;
    const short* W0Th = P + OFF_W0T;  const short* W0Tl = P + TOTE + OFF_W0T;

    if (tid < NP) {
        double e = exp(-(double)mp[tid]);
        invmd[tid] = e;
        invm[tid] = (float)e;
    }

    // ---- stage z: rsh/vsh fp32 + r split-bf16 into act rows 0..7 cols 0..63 ----
    const float* zb = z + sbase * ZD;
    #pragma unroll
    for (int k = 0; k < 4; ++k) {
        int e = k * 256 + tid;          // 0..1023
        int s = e >> 7, idx = e & 127;
        float val = zb[e];
        if (idx < 64) {
            rsh[idx][s] = val;
            unsigned short h = f2b(val);
            actH[s][idx] = h;
            actL[s][idx] = f2b(val - b2f(h));
        } else {
            vsh[idx - 64][s] = val;     // raw p for now
        }
    }
    __syncthreads();
    {   // p -> v = inv_m * p
        float* pv = &vsh[0][0];
        #pragma unroll
        for (int k = 0; k < 2; ++k) {
            int e = k * 256 + tid;
            pv[e] *= invm[e >> 4];
        }
    }
    __syncthreads();

    f32x4 acc[4];
    float p0s[4][4], p1s[4][4];
    const int nbase = wv * 64 + (L & 15);
    const bool rowok = (quad < 2);

    // helper-free epilogue macro-ish sequences written inline per pass

    // ---- L0: pre0 = r @ W0 + B0  (K=64) ----
    #pragma unroll
    for (int t = 0; t < 4; ++t) {
        float bb = B0[nbase + t * 16];
        acc[t] = (f32x4){bb, bb, bb, bb};
    }
    gemm_mf<2, 16, 4>(W0h, W0l, actH, actL, L, quad, wv, acc);
    #pragma unroll
    for (int t = 0; t < 4; ++t)
        #pragma unroll
        for (int r = 0; r < 4; ++r) p0s[t][r] = acc[t][r];
    __syncthreads();
    if (rowok) {
        #pragma unroll
        for (int t = 0; t < 4; ++t) {
            int n = nbase + t * 16;
            #pragma unroll
            for (int r = 0; r < 4; ++r) {
                int m = quad * 4 + r;
                float h = softplus_f(acc[t][r]);
                unsigned short hh = f2b(h);
                actH[m][n] = hh;
                actL[m][n] = f2b(h - b2f(hh));
            }
        }
    }
    __syncthreads();

    // ---- L1 ----
    #pragma unroll
    for (int t = 0; t < 4; ++t) {
        float bb = B1[nbase + t * 16];
        acc[t] = (f32x4){bb, bb, bb, bb};
    }
    gemm_mf<8, 16, 4>(W1h, W1l, actH, actL, L, quad, wv, acc);
    #pragma unroll
    for (int t = 0; t < 4; ++t)
        #pragma unroll
        for (int r = 0; r < 4; ++r) p1s[t][r] = acc[t][r];
    __syncthreads();
    if (rowok) {
        #pragma unroll
        for (int t = 0; t < 4; ++t) {
            int n = nbase + t * 16;
            #pragma unroll
            for (int r = 0; r < 4; ++r) {
                int m = quad * 4 + r;
                float h = softplus_f(acc[t][r]);
                unsigned short hh = f2b(h);
                actH[m][n] = hh;
                actL[m][n] = f2b(h - b2f(hh));
            }
        }
    }
    __syncthreads();

    // ---- L2 + head: dA = W3[n] * sigmoid(pre2) ----
    #pragma unroll
    for (int t = 0; t < 4; ++t) {
        float bb = B2[nbase + t * 16];
        acc[t] = (f32x4){bb, bb, bb, bb};
    }
    gemm_mf<8, 16, 4>(W2h, W2l, actH, actL, L, quad, wv, acc);
    __syncthreads();
    if (rowok) {
        #pragma unroll
        for (int t = 0; t < 4; ++t) {
            int n = nbase + t * 16;
            float w3 = W3[n];
            #pragma unroll
            for (int r = 0; r < 4; ++r) {
                int m = quad * 4 + r;
                float h = w3 * sigmoid_f(acc[t][r]);
                unsigned short hh = f2b(h);
                actH[m][n] = hh;
                actL[m][n] = f2b(h - b2f(hh));
            }
        }
    }
    __syncthreads();

    // ---- dB = sigmoid(p1) * (dA @ W2^T) ----
    #pragma unroll
    for (int t = 0; t < 4; ++t) acc[t] = (f32x4){0.f, 0.f, 0.f, 0.f};
    gemm_mf<8, 16, 4>(W2Th, W2Tl, actH, actL, L, quad, wv, acc);
    __syncthreads();
    if (rowok) {
        #pragma unroll
        for (int t = 0; t < 4; ++t) {
            int n = nbase + t * 16;
            #pragma unroll
            for (int r = 0; r < 4; ++r) {
                int m = quad * 4 + r;
                float h = acc[t][r] * sigmoid_f(p1s[t][r]);
                unsigned short hh = f2b(h);
                actH[m][n] = hh;
                actL[m][n] = f2b(h - b2f(hh));
            }
        }
    }
    __syncthreads();

    // ---- d0 = sigmoid(p0) * (dB @ W1^T) ----
    #pragma unroll
    for (int t = 0; t < 4; ++t) acc[t] = (f32x4){0.f, 0.f, 0.f, 0.f};
    gemm_mf<8, 16, 4>(W1Th, W1Tl, actH, actL, L, quad, wv, acc);
    __syncthreads();
    if (rowok) {
        #pragma unroll
        for (int t = 0; t < 4; ++t) {
            int n = nbase + t * 16;
            #pragma unroll
            for (int r = 0; r < 4; ++r) {
                int m = quad * 4 + r;
                float h = acc[t][r] * sigmoid_f(p0s[t][r]);
                unsigned short hh = f2b(h);
                actH[m][n] = hh;
                actL[m][n] = f2b(h - b2f(hh));
            }
        }
    }
    __syncthreads();

    // ---- g = d0 @ W0^T  (N=64): wave wv owns i in [16wv,16wv+16) ----
    acc[0] = (f32x4){0.f, 0.f, 0.f, 0.f};
    gemm_mf<8, 4, 1>(W0Th, W0Tl, actH, actL, L, quad, wv, acc);
    __syncthreads();
    if (rowok) {
        int i = wv * 16 + (L & 15);
        #pragma unroll
        for (int r = 0; r < 4; ++r) {
            int m = quad * 4 + r;
            gsh[i][m] = acc[0][r];
        }
    }
    __syncthreads();

    // ---- constraint assembly (fp64): S tridiag SPD, K tridiag antisym, b0, b1 ----
    {
        int s = tid >> 5, c = tid & 31;
        double gx, gy, gdx, gdy;
        if (c == 0) {
            double r0x = rsh[0][s], r0y = rsh[1][s];
            double v0x = vsh[0][s], v0y = vsh[1][s];
            gx = 2.0 * r0x; gy = 2.0 * r0y; gdx = 2.0 * v0x; gdy = 2.0 * v0y;
            Sdd[s][0] = invmd[0] * (gx * gx + gy * gy);
            b0d[s][0] = gx * v0x + gy * v0y;
            b1d[s][0] = gdx * v0x + gdy * v0y
                      - invmd[0] * (gx * (double)gsh[0][s] + gy * (double)gsh[1][s]);
        } else {
            int aa = 2 * (c - 1), b = 2 * c;
            double dvx = (double)vsh[aa][s] - (double)vsh[b][s];
            double dvy = (double)vsh[aa + 1][s] - (double)vsh[b + 1][s];
            gx = 2.0 * ((double)rsh[aa][s] - (double)rsh[b][s]);
            gy = 2.0 * ((double)rsh[aa + 1][s] - (double)rsh[b + 1][s]);
            gdx = 2.0 * dvx; gdy = 2.0 * dvy;
            Sdd[s][c] = (invmd[c - 1] + invmd[c]) * (gx * gx + gy * gy);
            b0d[s][c] = gx * dvx + gy * dvy;
            double mgx = invmd[c - 1] * (double)gsh[aa][s]     - invmd[c] * (double)gsh[b][s];
            double mgy = invmd[c - 1] * (double)gsh[aa + 1][s] - invmd[c] * (double)gsh[b + 1][s];
            b1d[s][c] = gdx * dvx + gdy * dvy - (gx * mgx + gy * mgy);
        }
        ge[s][c][0] = (float)gx;  ge[s][c][1] = (float)gy;
        gd[s][c][0] = (float)gdx; gd[s][c][1] = (float)gdy;
        __syncthreads();
        if (c < 31) {
            double g1x = ge[s][c + 1][0], g1y = ge[s][c + 1][1];
            double q1x = gd[s][c + 1][0], q1y = gd[s][c + 1][1];
            if (c == 0) {
                Sed[s][0] = invmd[0] * (gx * g1x + gy * g1y);
                Ked[s][0] = invmd[0] * ((gdx * g1x + gdy * g1y) - (gx * q1x + gy * q1y));
            } else {
                Sed[s][c] = -invmd[c] * (gx * g1x + gy * g1y);
                Ked[s][c] =  invmd[c] * ((gx * q1x + gy * q1y) - (gdx * g1x + gdy * g1y));
            }
        }
    }
    __syncthreads();

    // ---- fp64 Thomas: factor S, solve S X1 = b0 (in place in b0d) ----
    if (tid < SPB) {
        int s = tid;
        double d = Sdd[s][0];
        if (d == 0.0) d = 1e-300;
        dinv[s][0] = 1.0 / d;
        double y = b0d[s][0];
        for (int c = 1; c < NP; ++c) {
            double e = Sed[s][c - 1];
            double w = e * dinv[s][c - 1];
            wfac[s][c - 1] = w;
            d = Sdd[s][c] - w * e;
            if (d == 0.0) d = 1e-300;
            dinv[s][c] = 1.0 / d;
            y = b0d[s][c] - w * y;
            b0d[s][c] = y;
        }
        double x = b0d[s][31] * dinv[s][31];
        b0d[s][31] = x;
        for (int c = 30; c >= 0; --c) {
            x = (b0d[s][c] - Sed[s][c] * x) * dinv[s][c];
            b0d[s][c] = x;
        }
    }
    __syncthreads();

    // ---- rhs2 = K X1 - b1 (in place in b1d) ----
    {
        int s = tid >> 5, c = tid & 31;
        double kx = 0.0;
        if (c < 31) kx += Ked[s][c] * b0d[s][c + 1];
        if (c > 0)  kx -= Ked[s][c - 1] * b0d[s][c - 1];
        b1d[s][c] = kx - b1d[s][c];
    }
    __syncthreads();

    // ---- solve S X0 = rhs2 with stored factors (in place in b1d) ----
    if (tid < SPB) {
        int s = tid;
        double y = b1d[s][0];
        for (int c = 1; c < NP; ++c) {
            y = b1d[s][c] - wfac[s][c - 1] * y;
            b1d[s][c] = y;
        }
        double x = b1d[s][31] * dinv[s][31];
        b1d[s][31] = x;
        for (int c = 30; c >= 0; --c) {
            x = (b1d[s][c] - Sed[s][c] * x) * dinv[s][c];
            b1d[s][c] = x;
        }
    }
    __syncthreads();

    // ---- output: [v - M^-1 G X1 ; -g + G X0 + Gdot X1]   (X1=b0d, X0=b1d) ----
    float* ob = out + sbase * ZD;
    #pragma unroll
    for (int k = 0; k < 4; ++k) {
        int e = k * 256 + tid;
        int s = e >> 7, idx = e & 127;
        int j = idx & 63;
        int n = j >> 1, d = j & 1;
        float res;
        if (idx < 64) {
            double Gx1 = (n == 0) ? (double)ge[s][0][d] * b0d[s][0]
                                  : -(double)ge[s][n][d] * b0d[s][n];
            if (n < 31) Gx1 += (double)ge[s][n + 1][d] * b0d[s][n + 1];
            res = (float)((double)vsh[j][s] - invmd[n] * Gx1);
        } else {
            double Gx0 = (n == 0) ? (double)ge[s][0][d] * b1d[s][0]
                                  : -(double)ge[s][n][d] * b1d[s][n];
            if (n < 31) Gx0 += (double)ge[s][n + 1][d] * b1d[s][n + 1];
            double Gd1 = (n == 0) ? (double)gd[s][0][d] * b0d[s][0]
                                  : -(double)gd[s][n][d] * b0d[s][n];
            if (n < 31) Gd1 += (double)gd[s][n + 1][d] * b0d[s][n + 1];
            res = (float)(-(double)gsh[j][s] + Gx0 + Gd1);
        }
        ob[e] = res;
    }
}

extern "C" void kernel_launch(void* const* d_in, const int* in_sizes, int n_in,
                              void* d_out, int out_size, void* d_ws, size_t ws_size,
                              hipStream_t stream) {
    // inputs: 0=t, 1=z, 2=m_params, 3=W0, 4=b0, 5=W1, 6=b1, 7=W2, 8=b2, 9=W3, 10=b3
    const float* z  = (const float*)d_in[1];
    const float* mp = (const float*)d_in[2];
    const float* W0 = (const float*)d_in[3];
    const float* B0 = (const float*)d_in[4];
    const float* W1 = (const float*)d_in[5];
    const float* B1 = (const float*)d_in[6];
    const float* W2 = (const float*)d_in[7];
    const float* B2 = (const float*)d_in[8];
    const float* W3 = (const float*)d_in[9];

    short* P = (short*)d_ws;   // 2*TOTE bf16 elements = 1.15 MB packed weights

    prep_pack<<<144, 256, 0, stream>>>(W0, W1, W2, P);
    chnn_main<<<NBLK, 256, 0, stream>>>(z, mp, B0, B1, B2, W3, P, (float*)d_out);
}

// Round 8
// 129.033 us; speedup vs baseline: 1.2619x; 1.0586x over previous
//
#include <hip/hip_runtime.h>

#define ZD   128
#define NP   32
#define SPB  8
#define NBLK (4096 / SPB)

typedef __attribute__((ext_vector_type(8))) short bf16x8;   // 8 bf16 = 4 VGPRs
typedef __attribute__((ext_vector_type(4))) float f32x4;

// packed-weight element offsets (bf16 elements); lo copies at +TOTE
#define OFF_W0   0
#define OFF_W1   16384
#define OFF_W2   81920
#define OFF_W2T  147456
#define OFF_W1T  212992
#define OFF_W0T  278528
#define TOTE     294912

__device__ __forceinline__ float softplus_f(float x) {   // hw exp/log, ~1e-6 abs
    float e = __expf(-fabsf(x));
    return fmaxf(x, 0.0f) + __logf(1.0f + e);
}
__device__ __forceinline__ float sigmoid_f(float x) {
    return 1.0f / (1.0f + __expf(-x));
}
__device__ __forceinline__ unsigned short f2b(float f) {   // RNE float->bf16
    unsigned int u = __float_as_uint(f);
    unsigned int r = (u + 0x7FFFu + ((u >> 16) & 1u)) >> 16;
    return (unsigned short)r;
}
__device__ __forceinline__ float b2f(unsigned short h) {
    return __uint_as_float(((unsigned int)h) << 16);
}

// ---- pack weights (and transposes) into MFMA B-fragment order, split hi/lo ----
__global__ void prep_pack(const float* __restrict__ W0,
                          const float* __restrict__ W1,
                          const float* __restrict__ W2,
                          short* __restrict__ P) {
    int T = blockIdx.x * 256 + threadIdx.x;
    if (T >= 36864) return;
    const float* src; int base, NT, trans, lu, t = T;
    if (t < 2048)               { src = W0; base = OFF_W0;  NT = 16; trans = 0; lu = t; }
    else if ((t -= 2048) < 8192){ src = W1; base = OFF_W1;  NT = 16; trans = 0; lu = t; }
    else if ((t -= 8192) < 8192){ src = W2; base = OFF_W2;  NT = 16; trans = 0; lu = t; }
    else if ((t -= 8192) < 8192){ src = W2; base = OFF_W2T; NT = 16; trans = 1; lu = t; }
    else if ((t -= 8192) < 8192){ src = W1; base = OFF_W1T; NT = 16; trans = 1; lu = t; }
    else              { t -= 8192; src = W0; base = OFF_W0T; NT = 4; trans = 1; lu = t; }
    int frag = lu >> 6, lane = lu & 63;
    int kb = frag / NT, nt = frag - kb * NT;
    int n  = nt * 16 + (lane & 15);
    int k0 = kb * 32 + ((lane >> 4) << 3);
    int N  = NT * 16;
    bf16x8 hv, lv;
    #pragma unroll
    for (int j = 0; j < 8; ++j) {
        int k = k0 + j;
        float w = trans ? src[n * 256 + k] : src[k * N + n];
        unsigned short h = f2b(w);
        unsigned short l = f2b(w - b2f(h));
        hv[j] = (short)h;
        lv[j] = (short)l;
    }
    ((bf16x8*)(P + base))[lu]        = hv;
    ((bf16x8*)(P + TOTE + base))[lu] = lv;
}

// split-bf16 GEMM pass: acc[t] += A(act) x B(packed), 3 MFMAs per fragment.
template<int KB, int NT, int TPW>
__device__ __forceinline__ void gemm_mf(const short* __restrict__ BH,
                                        const short* __restrict__ BL,
                                        const unsigned short (*aH)[264],
                                        const unsigned short (*aL)[264],
                                        int L, int quad, int wv, f32x4* acc)
{
    #pragma unroll
    for (int kb = 0; kb < KB; ++kb) {
        bf16x8 ah = *(const bf16x8*)&aH[L & 15][kb * 32 + quad * 8];
        bf16x8 al = *(const bf16x8*)&aL[L & 15][kb * 32 + quad * 8];
        bf16x8 bh[TPW], bl[TPW];
        #pragma unroll
        for (int t = 0; t < TPW; ++t) {
            int frag = kb * NT + wv * TPW + t;
            bh[t] = ((const bf16x8*)BH)[frag * 64 + L];
            bl[t] = ((const bf16x8*)BL)[frag * 64 + L];
        }
        #pragma unroll
        for (int t = 0; t < TPW; ++t) {
            acc[t] = __builtin_amdgcn_mfma_f32_16x16x32_bf16(ah, bh[t], acc[t], 0, 0, 0);
            acc[t] = __builtin_amdgcn_mfma_f32_16x16x32_bf16(ah, bl[t], acc[t], 0, 0, 0);
            acc[t] = __builtin_amdgcn_mfma_f32_16x16x32_bf16(al, bh[t], acc[t], 0, 0, 0);
        }
    }
}

__global__ __launch_bounds__(256, 2) void chnn_main(
    const float* __restrict__ z, const float* __restrict__ mp,
    const float* __restrict__ B0, const float* __restrict__ B1,
    const float* __restrict__ B2, const float* __restrict__ W3,
    const short* __restrict__ P,
    float* __restrict__ out)
{
    __shared__ __align__(16) unsigned short actH[16][264];
    __shared__ __align__(16) unsigned short actL[16][264];
    __shared__ __align__(16) float rsh[64][SPB];
    __shared__ __align__(16) float vsh[64][SPB];
    __shared__ __align__(16) float gsh[64][SPB];
    __shared__ float invm[NP];
    __shared__ double invmd[NP];
    __shared__ float ge[SPB][NP][2], gd[SPB][NP][2];
    __shared__ double Sdd[SPB][NP], Sed[SPB][NP], Ked[SPB][NP];
    __shared__ double b0d[SPB][NP], b1d[SPB][NP];   // become X1, X0 in place
    __shared__ double wfac[SPB][NP], dinv[SPB][NP];

    const int tid  = threadIdx.x;
    const int L    = tid & 63;
    const int wv   = tid >> 6;
    const int quad = L >> 4;
    const long sbase = (long)blockIdx.x * SPB;

    const short* W0h  = P + OFF_W0;   const short* W0l  = P + TOTE + OFF_W0;
    const short* W1h  = P + OFF_W1;   const short* W1l  = P + TOTE + OFF_W1;
    const short* W2h  = P + OFF_W2;   const short* W2l  = P + TOTE + OFF_W2;
    const short* W2Th = P + OFF_W2T;  const short* W2Tl = P + TOTE + OFF_W2T;
    const short* W1Th = P + OFF_W1T;  const short* W1Tl = P + TOTE + OFF_W1T;
    const short* W0Th = P + OFF_W0T;  const short* W0Tl = P + TOTE + OFF_W0T;

    if (tid < NP) {
        double e = exp(-(double)mp[tid]);
        invmd[tid] = e;
        invm[tid] = (float)e;
    }

    // ---- stage z ----
    const float* zb = z + sbase * ZD;
    #pragma unroll
    for (int k = 0; k < 4; ++k) {
        int e = k * 256 + tid;
        int s = e >> 7, idx = e & 127;
        float val = zb[e];
        if (idx < 64) {
            rsh[idx][s] = val;
            unsigned short h = f2b(val);
            actH[s][idx] = h;
            actL[s][idx] = f2b(val - b2f(h));
        } else {
            vsh[idx - 64][s] = val;
        }
    }
    __syncthreads();
    {
        float* pv = &vsh[0][0];
        #pragma unroll
        for (int k = 0; k < 2; ++k) {
            int e = k * 256 + tid;
            pv[e] *= invm[e >> 4];
        }
    }
    __syncthreads();

    f32x4 acc[4];
    float p0s[4][4], p1s[4][4];
    const int nbase = wv * 64 + (L & 15);
    const bool rowok = (quad < 2);

    // ---- L0 ----
    #pragma unroll
    for (int t = 0; t < 4; ++t) {
        float bb = B0[nbase + t * 16];
        acc[t] = (f32x4){bb, bb, bb, bb};
    }
    gemm_mf<2, 16, 4>(W0h, W0l, actH, actL, L, quad, wv, acc);
    #pragma unroll
    for (int t = 0; t < 4; ++t)
        #pragma unroll
        for (int r = 0; r < 4; ++r) p0s[t][r] = acc[t][r];
    __syncthreads();
    if (rowok) {
        #pragma unroll
        for (int t = 0; t < 4; ++t) {
            int n = nbase + t * 16;
            #pragma unroll
            for (int r = 0; r < 4; ++r) {
                int m = quad * 4 + r;
                float h = softplus_f(acc[t][r]);
                unsigned short hh = f2b(h);
                actH[m][n] = hh;
                actL[m][n] = f2b(h - b2f(hh));
            }
        }
    }
    __syncthreads();

    // ---- L1 ----
    #pragma unroll
    for (int t = 0; t < 4; ++t) {
        float bb = B1[nbase + t * 16];
        acc[t] = (f32x4){bb, bb, bb, bb};
    }
    gemm_mf<8, 16, 4>(W1h, W1l, actH, actL, L, quad, wv, acc);
    #pragma unroll
    for (int t = 0; t < 4; ++t)
        #pragma unroll
        for (int r = 0; r < 4; ++r) p1s[t][r] = acc[t][r];
    __syncthreads();
    if (rowok) {
        #pragma unroll
        for (int t = 0; t < 4; ++t) {
            int n = nbase + t * 16;
            #pragma unroll
            for (int r = 0; r < 4; ++r) {
                int m = quad * 4 + r;
                float h = softplus_f(acc[t][r]);
                unsigned short hh = f2b(h);
                actH[m][n] = hh;
                actL[m][n] = f2b(h - b2f(hh));
            }
        }
    }
    __syncthreads();

    // ---- L2 + head: dA = W3[n] * sigmoid(pre2) ----
    #pragma unroll
    for (int t = 0; t < 4; ++t) {
        float bb = B2[nbase + t * 16];
        acc[t] = (f32x4){bb, bb, bb, bb};
    }
    gemm_mf<8, 16, 4>(W2h, W2l, actH, actL, L, quad, wv, acc);
    __syncthreads();
    if (rowok) {
        #pragma unroll
        for (int t = 0; t < 4; ++t) {
            int n = nbase + t * 16;
            float w3 = W3[n];
            #pragma unroll
            for (int r = 0; r < 4; ++r) {
                int m = quad * 4 + r;
                float h = w3 * sigmoid_f(acc[t][r]);
                unsigned short hh = f2b(h);
                actH[m][n] = hh;
                actL[m][n] = f2b(h - b2f(hh));
            }
        }
    }
    __syncthreads();

    // ---- dB = sigmoid(p1) * (dA @ W2^T) ----
    #pragma unroll
    for (int t = 0; t < 4; ++t) acc[t] = (f32x4){0.f, 0.f, 0.f, 0.f};
    gemm_mf<8, 16, 4>(W2Th, W2Tl, actH, actL, L, quad, wv, acc);
    __syncthreads();
    if (rowok) {
        #pragma unroll
        for (int t = 0; t < 4; ++t) {
            int n = nbase + t * 16;
            #pragma unroll
            for (int r = 0; r < 4; ++r) {
                int m = quad * 4 + r;
                float h = acc[t][r] * sigmoid_f(p1s[t][r]);
                unsigned short hh = f2b(h);
                actH[m][n] = hh;
                actL[m][n] = f2b(h - b2f(hh));
            }
        }
    }
    __syncthreads();

    // ---- d0 = sigmoid(p0) * (dB @ W1^T) ----
    #pragma unroll
    for (int t = 0; t < 4; ++t) acc[t] = (f32x4){0.f, 0.f, 0.f, 0.f};
    gemm_mf<8, 16, 4>(W1Th, W1Tl, actH, actL, L, quad, wv, acc);
    __syncthreads();
    if (rowok) {
        #pragma unroll
        for (int t = 0; t < 4; ++t) {
            int n = nbase + t * 16;
            #pragma unroll
            for (int r = 0; r < 4; ++r) {
                int m = quad * 4 + r;
                float h = acc[t][r] * sigmoid_f(p0s[t][r]);
                unsigned short hh = f2b(h);
                actH[m][n] = hh;
                actL[m][n] = f2b(h - b2f(hh));
            }
        }
    }
    __syncthreads();

    // ---- g = d0 @ W0^T  (N=64) ----
    acc[0] = (f32x4){0.f, 0.f, 0.f, 0.f};
    gemm_mf<8, 4, 1>(W0Th, W0Tl, actH, actL, L, quad, wv, acc);
    __syncthreads();
    if (rowok) {
        int i = wv * 16 + (L & 15);
        #pragma unroll
        for (int r = 0; r < 4; ++r) {
            int m = quad * 4 + r;
            gsh[i][m] = acc[0][r];
        }
    }
    __syncthreads();

    // ---- constraint assembly (fp64): S tridiag SPD, K tridiag antisym, b0, b1 ----
    {
        int s = tid >> 5, c = tid & 31;
        double gx, gy, gdx, gdy;
        if (c == 0) {
            double r0x = rsh[0][s], r0y = rsh[1][s];
            double v0x = vsh[0][s], v0y = vsh[1][s];
            gx = 2.0 * r0x; gy = 2.0 * r0y; gdx = 2.0 * v0x; gdy = 2.0 * v0y;
            Sdd[s][0] = invmd[0] * (gx * gx + gy * gy);
            b0d[s][0] = gx * v0x + gy * v0y;
            b1d[s][0] = gdx * v0x + gdy * v0y
                      - invmd[0] * (gx * (double)gsh[0][s] + gy * (double)gsh[1][s]);
        } else {
            int aa = 2 * (c - 1), b = 2 * c;
            double dvx = (double)vsh[aa][s] - (double)vsh[b][s];
            double dvy = (double)vsh[aa + 1][s] - (double)vsh[b + 1][s];
            gx = 2.0 * ((double)rsh[aa][s] - (double)rsh[b][s]);
            gy = 2.0 * ((double)rsh[aa + 1][s] - (double)rsh[b + 1][s]);
            gdx = 2.0 * dvx; gdy = 2.0 * dvy;
            Sdd[s][c] = (invmd[c - 1] + invmd[c]) * (gx * gx + gy * gy);
            b0d[s][c] = gx * dvx + gy * dvy;
            double mgx = invmd[c - 1] * (double)gsh[aa][s]     - invmd[c] * (double)gsh[b][s];
            double mgy = invmd[c - 1] * (double)gsh[aa + 1][s] - invmd[c] * (double)gsh[b + 1][s];
            b1d[s][c] = gdx * dvx + gdy * dvy - (gx * mgx + gy * mgy);
        }
        ge[s][c][0] = (float)gx;  ge[s][c][1] = (float)gy;
        gd[s][c][0] = (float)gdx; gd[s][c][1] = (float)gdy;
        __syncthreads();
        if (c < 31) {
            double g1x = ge[s][c + 1][0], g1y = ge[s][c + 1][1];
            double q1x = gd[s][c + 1][0], q1y = gd[s][c + 1][1];
            if (c == 0) {
                Sed[s][0] = invmd[0] * (gx * g1x + gy * g1y);
                Ked[s][0] = invmd[0] * ((gdx * g1x + gdy * g1y) - (gx * q1x + gy * q1y));
            } else {
                Sed[s][c] = -invmd[c] * (gx * g1x + gy * g1y);
                Ked[s][c] =  invmd[c] * ((gx * q1x + gy * q1y) - (gdx * g1x + gdy * g1y));
            }
        }
    }
    __syncthreads();

    // ---- fp64 Thomas: factor S, solve S X1 = b0 (in place in b0d) ----
    if (tid < SPB) {
        int s = tid;
        double d = Sdd[s][0];
        if (d == 0.0) d = 1e-300;
        dinv[s][0] = 1.0 / d;
        double y = b0d[s][0];
        for (int c = 1; c < NP; ++c) {
            double e = Sed[s][c - 1];
            double w = e * dinv[s][c - 1];
            wfac[s][c - 1] = w;
            d = Sdd[s][c] - w * e;
            if (d == 0.0) d = 1e-300;
            dinv[s][c] = 1.0 / d;
            y = b0d[s][c] - w * y;
            b0d[s][c] = y;
        }
        double x = b0d[s][31] * dinv[s][31];
        b0d[s][31] = x;
        for (int c = 30; c >= 0; --c) {
            x = (b0d[s][c] - Sed[s][c] * x) * dinv[s][c];
            b0d[s][c] = x;
        }
    }
    __syncthreads();

    // ---- rhs2 = K X1 - b1 (in place in b1d) ----
    {
        int s = tid >> 5, c = tid & 31;
        double kx = 0.0;
        if (c < 31) kx += Ked[s][c] * b0d[s][c + 1];
        if (c > 0)  kx -= Ked[s][c - 1] * b0d[s][c - 1];
        b1d[s][c] = kx - b1d[s][c];
    }
    __syncthreads();

    // ---- solve S X0 = rhs2 with stored factors (in place in b1d) ----
    if (tid < SPB) {
        int s = tid;
        double y = b1d[s][0];
        for (int c = 1; c < NP; ++c) {
            y = b1d[s][c] - wfac[s][c - 1] * y;
            b1d[s][c] = y;
        }
        double x = b1d[s][31] * dinv[s][31];
        b1d[s][31] = x;
        for (int c = 30; c >= 0; --c) {
            x = (b1d[s][c] - Sed[s][c] * x) * dinv[s][c];
            b1d[s][c] = x;
        }
    }
    __syncthreads();

    // ---- output: [v - M^-1 G X1 ; -g + G X0 + Gdot X1]   (X1=b0d, X0=b1d) ----
    float* ob = out + sbase * ZD;
    #pragma unroll
    for (int k = 0; k < 4; ++k) {
        int e = k * 256 + tid;
        int s = e >> 7, idx = e & 127;
        int j = idx & 63;
        int n = j >> 1, d = j & 1;
        float res;
        if (idx < 64) {
            double Gx1 = (n == 0) ? (double)ge[s][0][d] * b0d[s][0]
                                  : -(double)ge[s][n][d] * b0d[s][n];
            if (n < 31) Gx1 += (double)ge[s][n + 1][d] * b0d[s][n + 1];
            res = (float)((double)vsh[j][s] - invmd[n] * Gx1);
        } else {
            double Gx0 = (n == 0) ? (double)ge[s][0][d] * b1d[s][0]
                                  : -(double)ge[s][n][d] * b1d[s][n];
            if (n < 31) Gx0 += (double)ge[s][n + 1][d] * b1d[s][n + 1];
            double Gd1 = (n == 0) ? (double)gd[s][0][d] * b0d[s][0]
                                  : -(double)gd[s][n][d] * b0d[s][n];
            if (n < 31) Gd1 += (double)gd[s][n + 1][d] * b0d[s][n + 1];
            res = (float)(-(double)gsh[j][s] + Gx0 + Gd1);
        }
        ob[e] = res;
    }
}

extern "C" void kernel_launch(void* const* d_in, const int* in_sizes, int n_in,
                              void* d_out, int out_size, void* d_ws, size_t ws_size,
                              hipStream_t stream) {
    const float* z  = (const float*)d_in[1];
    const float* mp = (const float*)d_in[2];
    const float* W0 = (const float*)d_in[3];
    const float* B0 = (const float*)d_in[4];
    const float* W1 = (const float*)d_in[5];
    const float* B1 = (const float*)d_in[6];
    const float* W2 = (const float*)d_in[7];
    const float* B2 = (const float*)d_in[8];
    const float* W3 = (const float*)d_in[9];

    short* P = (short*)d_ws;   // 2*TOTE bf16 elements = 1.15 MB packed weights

    prep_pack<<<144, 256, 0, stream>>>(W0, W1, W2, P);
    chnn_main<<<NBLK, 256, 0, stream>>>(z, mp, B0, B1, B2, W3, P, (float*)d_out);
}